// Round 7
// baseline (526.103 us; speedup 1.0000x reference)
//
#include <hip/hip_runtime.h>
#include <cstddef>

#define EMBED   768
#define NHEADS  12
#define HDIM    64
#define KSZ     7
#define IMG_H   64
#define IMG_W   64
#define BATCH   8
#define NTOK    (BATCH*IMG_H*IMG_W)   /* 32768 */
#define QKV_N   (3*EMBED)             /* 2304  */

typedef __attribute__((ext_vector_type(8))) short  bf16x8;
typedef __attribute__((ext_vector_type(4))) float  f32x4;
typedef __attribute__((ext_vector_type(8))) unsigned short u16x8;
typedef __attribute__((ext_vector_type(4))) unsigned short u16x4;

__device__ __forceinline__ unsigned short f2bf(float f) {
    unsigned int u = __float_as_uint(f);
    u += 0x7FFFu + ((u >> 16) & 1u);      // RNE
    return (unsigned short)(u >> 16);
}

__device__ __forceinline__ void gload_lds16(const void* g, void* l) {
    __builtin_amdgcn_global_load_lds(
        (const __attribute__((address_space(1))) unsigned int*)g,
        (__attribute__((address_space(3))) unsigned int*)l, 16, 0, 0);
}

// ---------------- fp32 -> bf16 conversion ----------------
__global__ __launch_bounds__(256)
void cvt_bf16_kernel(const float* __restrict__ in, unsigned short* __restrict__ out, int n4)
{
    int i = blockIdx.x * 256 + threadIdx.x;
    if (i < n4) {
        float4 f = *(const float4*)(in + (size_t)i * 4);
        u16x4 o;
        o[0] = f2bf(f.x); o[1] = f2bf(f.y); o[2] = f2bf(f.z); o[3] = f2bf(f.w);
        *(u16x4*)(out + (size_t)i * 4) = o;
    }
}

// ---------------- bf16 MFMA GEMM v4: 256x256, 8 waves, BK=32, 3-buf counted pipeline ----
// v4 changes vs v3: (1) bn-fastest block order within each XCD (A-panel L2 reuse, B
// resident); (2) coalesced epilogue via per-wave LDS bounce (16B stores).
template<int BF16OUT>
__global__ __launch_bounds__(512)
void gemm256(const unsigned short* __restrict__ A, const unsigned short* __restrict__ W,
             const float* __restrict__ bias, void* __restrict__ outp,
             int M, int N, int K, int scaleN, float scale)
{
    __shared__ unsigned short lds[3 * 16384];   // 96 KiB: buf q at q*16384; B at +8192
    const int t_ = threadIdx.x;
    const int l = t_ & 63, w = t_ >> 6;
    const int wr2 = w >> 2, wc4 = w & 3;

    // block mapping: xcd = blockIdx.x & 7 (round-robin dispatch), loc bn-fastest so
    // consecutive blocks on one XCD share the A-panel (L2-hot) and B stays resident.
    const int nby = N >> 8;
    const int xcd = blockIdx.x & 7;
    const int loc = blockIdx.x >> 3;
    const int bm = (xcd * ((M >> 8) >> 3) + loc / nby) << 8;
    const int bn = (loc % nby) << 8;

    // staging source (quad-coalesced, slot-permuted; see v3 comment)
    const int kperm = ((l & 3) ^ ((l >> 3) & 3)) * 8;
    const unsigned short* gA = A + (size_t)(bm + w * 16 + (l >> 2)) * K + kperm;
    const unsigned short* gB = W + (size_t)(bn + w * 16 + (l >> 2)) * K + kperm;
    const size_t step8 = (size_t)128 * K;      // subtile index +8

    unsigned short* lA = lds + w * 512;        // + q + i*4096
    unsigned short* lB = lds + 8192 + w * 512;

    // fragment read offset (ushort units): row (l&15), slot (l>>4)^((l>>1)&3)
    const int foff = (l & 15) * 32 + (((l >> 4) ^ ((l >> 1) & 3)) * 8);
    const unsigned short* raw = lds + (wr2 * 8) * 512 + foff;
    const unsigned short* rbw = lds + 8192 + (wc4 * 4) * 512 + foff;

    f32x4 acc[8][4] = {};
    const int NT = K / 32;

    // prologue: stage tiles 0 and 1 (oldest-first), wait tile 0 (4 of 8 still in flight)
    gload_lds16(gA, lA);              gload_lds16(gA + step8, lA + 4096);
    gload_lds16(gB, lB);              gload_lds16(gB + step8, lB + 4096);
    gload_lds16(gA + 32, lA + 16384); gload_lds16(gA + step8 + 32, lA + 16384 + 4096);
    gload_lds16(gB + 32, lB + 16384); gload_lds16(gB + step8 + 32, lB + 16384 + 4096);
    asm volatile("s_waitcnt vmcnt(4)" ::: "memory");
    __builtin_amdgcn_s_barrier();

    for (int t = 0; t < NT; ++t) {
        const int q  = (t % 3) * 16384;
        const int qn = ((t + 2) % 3) * 16384;
        const bool pf = (t + 2 < NT);
        const int ko = t * 32 + 64;            // k-offset of tile t+2

        // ---- phase 1 (m-frags 0..3) ----
        if (pf) { gload_lds16(gA + ko, lA + qn); gload_lds16(gA + step8 + ko, lA + qn + 4096); }
        bf16x8 af0[4], bf[4];
        #pragma unroll
        for (int m = 0; m < 4; ++m) af0[m] = *(const bf16x8*)(raw + q + m * 512);
        #pragma unroll
        for (int n = 0; n < 4; ++n) bf[n]  = *(const bf16x8*)(rbw + q + n * 512);
        __builtin_amdgcn_s_barrier();
        __builtin_amdgcn_s_setprio(1);
        #pragma unroll
        for (int m = 0; m < 4; ++m)
            #pragma unroll
            for (int n = 0; n < 4; ++n)
                acc[m][n] = __builtin_amdgcn_mfma_f32_16x16x32_bf16(af0[m], bf[n], acc[m][n], 0, 0, 0);
        __builtin_amdgcn_s_setprio(0);
        __builtin_amdgcn_s_barrier();

        // ---- phase 2 (m-frags 4..7) ----
        if (pf) { gload_lds16(gB + ko, lB + qn); gload_lds16(gB + step8 + ko, lB + qn + 4096); }
        bf16x8 af1[4];
        #pragma unroll
        for (int m = 0; m < 4; ++m) af1[m] = *(const bf16x8*)(raw + q + (4 + m) * 512);
        __builtin_amdgcn_s_barrier();
        __builtin_amdgcn_s_setprio(1);
        #pragma unroll
        for (int m = 0; m < 4; ++m)
            #pragma unroll
            for (int n = 0; n < 4; ++n)
                acc[4 + m][n] = __builtin_amdgcn_mfma_f32_16x16x32_bf16(af1[m], bf[n], acc[4 + m][n], 0, 0, 0);
        __builtin_amdgcn_s_setprio(0);
        if (t < NT - 1) {
            if (pf) asm volatile("s_waitcnt vmcnt(4)" ::: "memory");
            else    asm volatile("s_waitcnt vmcnt(0)" ::: "memory");
            __builtin_amdgcn_s_barrier();
        }
    }

    // ---- epilogue: per-wave LDS bounce -> coalesced 16B stores ----
    __syncthreads();                           // all waves done with K-loop LDS
    const int cr = (l >> 4) * 4;
    const int cc = l & 15;
    const int g  = l >> 4;
    const int erd = l >> 2;                    // read row 0..15
    const int ecs = l & 3;                     // read col-chunk

    if (BF16OUT) {
        unsigned short* eb = lds + w * 1024;   // 2 KiB per wave
        unsigned short* out16 = (unsigned short*)outp;
        #pragma unroll 1
        for (int m = 0; m < 8; ++m) {
            #pragma unroll
            for (int n = 0; n < 4; ++n) {
                const int col = bn + wc4 * 64 + n * 16 + cc;
                const float bv = bias[col];
                const bool sc = col < scaleN;
                #pragma unroll
                for (int r = 0; r < 4; ++r) {
                    float v = acc[m][n][r] + bv;
                    if (sc) v *= scale;
                    eb[(cr + r) * 64 + ((n * 16 + cc) ^ (g << 4))] = f2bf(v);
                }
            }
            const int rowg = bm + wr2 * 128 + m * 16 + erd;
            const unsigned short* rp = eb + erd * 64 + ((ecs ^ (erd >> 2)) << 4);
            u16x8 v0 = *(const u16x8*)rp;
            u16x8 v1 = *(const u16x8*)(rp + 8);
            unsigned short* gp = out16 + (size_t)rowg * N + bn + wc4 * 64 + ecs * 16;
            *(u16x8*)gp = v0;
            *(u16x8*)(gp + 8) = v1;
        }
    } else {
        float* eb = (float*)(void*)lds + w * 1024;  // 4 KiB per wave
        float* outf = (float*)outp;
        #pragma unroll 1
        for (int m = 0; m < 8; ++m) {
            #pragma unroll
            for (int n = 0; n < 4; ++n) {
                const int col = bn + wc4 * 64 + n * 16 + cc;
                const float bv = bias[col];
                #pragma unroll
                for (int r = 0; r < 4; ++r)
                    eb[(cr + r) * 64 + ((n * 16 + cc) ^ (g << 3))] = acc[m][n][r] + bv;
            }
            const int rowg = bm + wr2 * 128 + m * 16 + erd;
            float* gp = outf + (size_t)rowg * N + bn + wc4 * 64 + ecs * 16;
            #pragma unroll
            for (int qq = 0; qq < 4; ++qq) {
                f32x4 vv = *(const f32x4*)(eb + erd * 64 + (((ecs * 16 + qq * 4) ^ ((erd >> 2) << 3))));
                *(f32x4*)(gp + qq * 4) = vv;
            }
        }
    }
}

// ---------------- MFMA neighborhood attention (verified round 4) ----------------
__global__ __launch_bounds__(256)
void natten_kernel(const unsigned short* __restrict__ qkv, unsigned short* __restrict__ attn_bf)
{
    __shared__ unsigned short smem[4 * 5888];   // per wave: K 32x72 + V^T 64x56
    const int t = threadIdx.x;
    const int w = t >> 6, l = t & 63;
    const int c15 = l & 15, g = l >> 4;
    const int blk = blockIdx.x;
    const int tg = blk & 15;
    const int h = (blk >> 4) % NHEADS;
    const int b = blk / (16 * NHEADS);
    const int ti = (tg >> 2) * 16, tj = (tg & 3) * 16;
    const int pi0 = ti + w * 4;
    const int ws = min(max(pi0 - 3, 0), IMG_H - 10);
    const int cs = min(max(tj - 3, 0), IMG_W - 22);
    const int pixbase = b * 4096;

    unsigned short* Kl = smem + w * 5888;
    unsigned short* Vt = Kl + 2304;

    const int pj = tj + c15;
    const int sj = min(max(pj - 3, 0), IMG_W - KSZ);
    const unsigned int cm = 0x7Fu << (sj - cs);
    unsigned int rm[4];
    #pragma unroll
    for (int qt = 0; qt < 4; ++qt) {
        int si = min(max(pi0 + qt - 3, 0), IMG_H - KSZ);
        rm[qt] = 0x7Fu << (si - ws);
    }

    bf16x8 qf[4][2];
    #pragma unroll
    for (int qt = 0; qt < 4; ++qt)
        #pragma unroll
        for (int dh = 0; dh < 2; ++dh)
            qf[qt][dh] = *(const bf16x8*)(qkv +
                (size_t)(pixbase + (pi0 + qt) * 64 + tj + c15) * QKV_N + h * HDIM + dh * 32 + g * 8);

    const int sr = l & 31;
    const int h5 = l >> 5;
    const int sig = ((sr & 12) << 1) | ((sr & 16) >> 2) | (sr & 3);  // slot perm 8g+4t+j

    u16x8 kst[4], vst[4];

    {
        int ur = sr / 22, uc = sr - ur * 22;
        int prow = min(ws + ur, IMG_H - 1);
        const u16x8* gk = (const u16x8*)(qkv +
            (size_t)(pixbase + prow * 64 + cs + uc) * QKV_N + EMBED + h * HDIM + h5 * 32);
        #pragma unroll
        for (int i = 0; i < 4; ++i) { kst[i] = gk[i]; vst[i] = gk[i + 96]; }
    }
    #pragma unroll
    for (int i = 0; i < 4; ++i) *(u16x8*)(Kl + sr * 72 + h5 * 32 + i * 8) = kst[i];
    #pragma unroll
    for (int i = 0; i < 4; ++i)
        #pragma unroll
        for (int e = 0; e < 8; ++e)
            Vt[(h5 * 32 + i * 8 + e) * 56 + sig] = vst[i][e];

    f32x4 oacc[4][4] = {};
    float spart[4] = {0.f, 0.f, 0.f, 0.f};

    #pragma unroll 1
    for (int C = 0; C < 7; ++C) {
        if (C < 6) {
            int kk = (C + 1) * 32 + sr;
            int ur = kk / 22, uc = kk - ur * 22;
            int prow = min(ws + ur, IMG_H - 1);
            const u16x8* gk = (const u16x8*)(qkv +
                (size_t)(pixbase + prow * 64 + cs + uc) * QKV_N + EMBED + h * HDIM + h5 * 32);
            #pragma unroll
            for (int i = 0; i < 4; ++i) { kst[i] = gk[i]; vst[i] = gk[i + 96]; }
        }

        bf16x8 ka[2][2], vb[4];
        #pragma unroll
        for (int kt = 0; kt < 2; ++kt)
            #pragma unroll
            for (int dh = 0; dh < 2; ++dh)
                ka[kt][dh] = *(const bf16x8*)(Kl + (kt * 16 + c15) * 72 + dh * 32 + g * 8);
        #pragma unroll
        for (int dt = 0; dt < 4; ++dt)
            vb[dt] = *(const bf16x8*)(Vt + (dt * 16 + c15) * 56 + g * 8);

        int kk0 = C * 32 + 4 * g;
        int a22 = kk0 / 22;
        int uc0 = kk0 - a22 * 22;
        int urx[2][4]; unsigned int cb[2][4];
        #pragma unroll
        for (int kt = 0; kt < 2; ++kt)
            #pragma unroll
            for (int r = 0; r < 4; ++r) {
                int x = uc0 + kt * 16 + r;
                int wrp = x >= 22;
                int uc = x - (wrp ? 22 : 0);
                urx[kt][r] = a22 + wrp;
                cb[kt][r] = (cm >> uc) & 1u;
            }

        #pragma unroll
        for (int qt = 0; qt < 4; ++qt) {
            f32x4 s0 = {}, s1 = {};
            s0 = __builtin_amdgcn_mfma_f32_16x16x32_bf16(ka[0][0], qf[qt][0], s0, 0, 0, 0);
            s0 = __builtin_amdgcn_mfma_f32_16x16x32_bf16(ka[0][1], qf[qt][1], s0, 0, 0, 0);
            s1 = __builtin_amdgcn_mfma_f32_16x16x32_bf16(ka[1][0], qf[qt][0], s1, 0, 0, 0);
            s1 = __builtin_amdgcn_mfma_f32_16x16x32_bf16(ka[1][1], qf[qt][1], s1, 0, 0, 0);
            float p[2][4];
            #pragma unroll
            for (int r = 0; r < 4; ++r) {
                float e0 = exp2f(s0[r]);
                float e1 = exp2f(s1[r]);
                p[0][r] = ((rm[qt] >> urx[0][r]) & cb[0][r]) ? e0 : 0.f;
                p[1][r] = ((rm[qt] >> urx[1][r]) & cb[1][r]) ? e1 : 0.f;
                spart[qt] += p[0][r] + p[1][r];
            }
            unsigned int pk[4];
            asm("v_cvt_pk_bf16_f32 %0, %1, %2" : "=v"(pk[0]) : "v"(p[0][0]), "v"(p[0][1]));
            asm("v_cvt_pk_bf16_f32 %0, %1, %2" : "=v"(pk[1]) : "v"(p[0][2]), "v"(p[0][3]));
            asm("v_cvt_pk_bf16_f32 %0, %1, %2" : "=v"(pk[2]) : "v"(p[1][0]), "v"(p[1][1]));
            asm("v_cvt_pk_bf16_f32 %0, %1, %2" : "=v"(pk[3]) : "v"(p[1][2]), "v"(p[1][3]));
            bf16x8 pa = *(bf16x8*)pk;
            #pragma unroll
            for (int dt = 0; dt < 4; ++dt)
                oacc[qt][dt] = __builtin_amdgcn_mfma_f32_16x16x32_bf16(pa, vb[dt], oacc[qt][dt], 0, 0, 0);
        }

        if (C < 6) {
            #pragma unroll
            for (int i = 0; i < 4; ++i) *(u16x8*)(Kl + sr * 72 + h5 * 32 + i * 8) = kst[i];
            #pragma unroll
            for (int i = 0; i < 4; ++i)
                #pragma unroll
                for (int e = 0; e < 8; ++e)
                    Vt[(h5 * 32 + i * 8 + e) * 56 + sig] = vst[i][e];
        }
    }

    #pragma unroll
    for (int qt = 0; qt < 4; ++qt) {
        float s = spart[qt];
        s += __shfl_xor(s, 16);
        s += __shfl_xor(s, 32);
        #pragma unroll
        for (int r = 0; r < 4; ++r) {
            float sb = __shfl(s, 4 * g + r);
            float inv = __builtin_amdgcn_rcpf(sb);
            size_t obase = (size_t)(pixbase + (pi0 + qt) * 64 + tj + 4 * g + r) * EMBED
                         + h * HDIM + c15;
            #pragma unroll
            for (int dt = 0; dt < 4; ++dt)
                attn_bf[obase + dt * 16] = f2bf(oacc[qt][dt][r] * inv);
        }
    }
}

// ---------------- launch ----------------
extern "C" void kernel_launch(void* const* d_in, const int* in_sizes, int n_in,
                              void* d_out, int out_size, void* d_ws, size_t ws_size,
                              hipStream_t stream)
{
    const float* x      = (const float*)d_in[0];
    const float* w_qkv  = (const float*)d_in[1];
    const float* b_qkv  = (const float*)d_in[2];
    const float* w_proj = (const float*)d_in[3];
    const float* b_proj = (const float*)d_in[4];
    float* out = (float*)d_out;

    // workspace (~206 MB)
    char* p = (char*)d_ws;
    unsigned short* qkv = (unsigned short*)p;     p += (size_t)NTOK * QKV_N * 2;       // 151 MB
    unsigned short* xbf = (unsigned short*)p;     // aliased: x_bf then attn_bf
    unsigned short* attn_bf = xbf;                p += (size_t)NTOK * EMBED * 2;       // 50 MB
    unsigned short* wq_bf = (unsigned short*)p;   p += (size_t)QKV_N * EMBED * 2;      // 3.5 MB
    unsigned short* wp_bf = (unsigned short*)p;

    const float scale = 0.125f * 1.44269504088896f;  // HDIM^-0.5 * log2(e)

    {
        int n4 = NTOK * EMBED / 4;
        cvt_bf16_kernel<<<(n4 + 255) / 256, 256, 0, stream>>>(x, xbf, n4);
        n4 = QKV_N * EMBED / 4;
        cvt_bf16_kernel<<<(n4 + 255) / 256, 256, 0, stream>>>(w_qkv, wq_bf, n4);
        n4 = EMBED * EMBED / 4;
        cvt_bf16_kernel<<<(n4 + 255) / 256, 256, 0, stream>>>(w_proj, wp_bf, n4);
    }

    {
        // GEMM1: M=32768, N=2304 -> 1152 blocks (144 per XCD)
        gemm256<1><<<(NTOK / 256) * (QKV_N / 256), 512, 0, stream>>>(
            xbf, wq_bf, b_qkv, qkv, NTOK, QKV_N, EMBED, EMBED, scale);
    }

    natten_kernel<<<BATCH * NHEADS * 16, 256, 0, stream>>>(qkv, attn_bf);

    {
        // GEMM2: M=32768, N=768 -> 384 blocks (48 per XCD)
        gemm256<0><<<(NTOK / 256) * (EMBED / 256), 512, 0, stream>>>(
            attn_bf, wp_bf, b_proj, out, NTOK, EMBED, EMBED, 0, 1.0f);
    }
}

// Round 8
// 366.410 us; speedup vs baseline: 1.4358x; 1.4358x over previous
//
#include <hip/hip_runtime.h>
#include <cstddef>

#define EMBED   768
#define NHEADS  12
#define HDIM    64
#define KSZ     7
#define IMG_H   64
#define IMG_W   64
#define BATCH   8
#define NTOK    (BATCH*IMG_H*IMG_W)   /* 32768 */
#define QKV_N   (3*EMBED)             /* 2304  */

typedef __attribute__((ext_vector_type(8))) short  bf16x8;
typedef __attribute__((ext_vector_type(4))) float  f32x4;
typedef __attribute__((ext_vector_type(8))) unsigned short u16x8;
typedef __attribute__((ext_vector_type(4))) unsigned short u16x4;

__device__ __forceinline__ unsigned short f2bf(float f) {
    unsigned int u = __float_as_uint(f);
    u += 0x7FFFu + ((u >> 16) & 1u);      // RNE
    return (unsigned short)(u >> 16);
}

__device__ __forceinline__ void gload_lds16(const void* g, void* l) {
    __builtin_amdgcn_global_load_lds(
        (const __attribute__((address_space(1))) unsigned int*)g,
        (__attribute__((address_space(3))) unsigned int*)l, 16, 0, 0);
}

// ---------------- fp32 -> bf16 conversion ----------------
__global__ __launch_bounds__(256)
void cvt_bf16_kernel(const float* __restrict__ in, unsigned short* __restrict__ out, int n4)
{
    int i = blockIdx.x * 256 + threadIdx.x;
    if (i < n4) {
        float4 f = *(const float4*)(in + (size_t)i * 4);
        u16x4 o;
        o[0] = f2bf(f.x); o[1] = f2bf(f.y); o[2] = f2bf(f.z); o[3] = f2bf(f.w);
        *(u16x4*)(out + (size_t)i * 4) = o;
    }
}

// ---------------- bf16 MFMA GEMM v5: 128x128, 4 waves, 16 KB single-buf, 2-barrier ----
// m97-proven occupancy structure (~3 blocks/CU; cross-block overlap covers the
// barrier drain) + round-6-proven conflict-free slot-permuted LDS:
//   subtile s (16 rows x 32 k) at s*1024 B; entry (r, kchunk k) at byte
//   r*64 + ((k ^ ((r>>1)&3))<<4).
//   - gload write is lane-linear (lane l -> byte l*16) => global source row l>>2
//     (quad-coalesced 64 B), kchunk (l&3)^((l>>3)&3).
//   - ds_read lane l (r=l&15, k=l>>4) spreads the 64 lanes over all 8 slots -> 0 conflicts.
// Scalar epilogue (proven WRITE_SIZE == data size; vector LDS-bounce amplified 5x).
template<int BF16OUT>
__global__ __launch_bounds__(256)
void gemm128(const unsigned short* __restrict__ A, const unsigned short* __restrict__ W,
             const float* __restrict__ bias, void* __restrict__ outp,
             int M, int N, int K, int scaleN, float scale)
{
    __shared__ unsigned short lds[8192];   // 16 KiB: A subtiles 0..7 at 0, B at +4096
    const int t = threadIdx.x;
    const int l = t & 63, w = t >> 6;
    const int wr = (w >> 1) * 64, wc = (w & 1) * 64;

    // XCD swizzle (round-6 proven): consecutive blocks on an XCD share bn (B-panel hot)
    const int nbx = M >> 7;
    const int cpx = gridDim.x >> 3;
    const int lin = blockIdx.x;
    const int swz = (lin & 7) * cpx + (lin >> 3);
    const int bm = (swz % nbx) << 7;
    const int bn = (swz / nbx) << 7;

    // staging source (quad-coalesced, slot-permuted)
    const int kperm = ((l & 3) ^ ((l >> 3) & 3)) * 8;
    const unsigned short* gA0 = A + (size_t)(bm + w * 16 + (l >> 2)) * K + kperm;
    const unsigned short* gB0 = W + (size_t)(bn + w * 16 + (l >> 2)) * K + kperm;
    const size_t step4 = (size_t)64 * K;            // subtile index +4
    unsigned short* lA0 = lds + w * 512;
    unsigned short* lA1 = lds + (w + 4) * 512;
    unsigned short* lB0 = lds + 4096 + w * 512;
    unsigned short* lB1 = lds + 4096 + (w + 4) * 512;

    // fragment read bases: row (l&15), slot (l>>4)^((l>>1)&3)
    const int foff = (l & 15) * 32 + (((l >> 4) ^ ((l >> 1) & 3)) * 8);
    const unsigned short* raw = lds + (wr >> 4) * 512 + foff;
    const unsigned short* rbw = lds + 4096 + (wc >> 4) * 512 + foff;

    f32x4 acc[4][4] = {};
    const int NT = K / 32;

    for (int ts = 0; ts < NT; ++ts) {
        const int k0 = ts * 32;
        __syncthreads();                            // prev iter's ds_reads done
        gload_lds16(gA0 + k0, lA0);
        gload_lds16(gA0 + step4 + k0, lA1);
        gload_lds16(gB0 + k0, lB0);
        gload_lds16(gB0 + step4 + k0, lB1);
        __syncthreads();                            // compiler drains vmcnt before barrier
        bf16x8 af[4], bfr[4];
        #pragma unroll
        for (int i = 0; i < 4; ++i) af[i]  = *(const bf16x8*)(raw + i * 512);
        #pragma unroll
        for (int j = 0; j < 4; ++j) bfr[j] = *(const bf16x8*)(rbw + j * 512);
        #pragma unroll
        for (int i = 0; i < 4; ++i)
            #pragma unroll
            for (int j = 0; j < 4; ++j)
                acc[i][j] = __builtin_amdgcn_mfma_f32_16x16x32_bf16(af[i], bfr[j], acc[i][j], 0, 0, 0);
    }

    // scalar epilogue (proven write-combining)
    const int cr = (l >> 4) * 4;
    const int cc = l & 15;
    #pragma unroll
    for (int i = 0; i < 4; ++i) {
        #pragma unroll
        for (int j = 0; j < 4; ++j) {
            const int col = bn + wc + j * 16 + cc;
            const float bv = bias[col];
            const bool sc = col < scaleN;
            #pragma unroll
            for (int r = 0; r < 4; ++r) {
                const int row = bm + wr + i * 16 + cr + r;
                float v = acc[i][j][r] + bv;
                if (sc) v *= scale;
                if (BF16OUT) ((unsigned short*)outp)[(size_t)row * N + col] = f2bf(v);
                else         ((float*)outp)[(size_t)row * N + col] = v;
            }
        }
    }
}

// ---------------- MFMA neighborhood attention (verified round 4) ----------------
__global__ __launch_bounds__(256)
void natten_kernel(const unsigned short* __restrict__ qkv, unsigned short* __restrict__ attn_bf)
{
    __shared__ unsigned short smem[4 * 5888];   // per wave: K 32x72 + V^T 64x56
    const int t = threadIdx.x;
    const int w = t >> 6, l = t & 63;
    const int c15 = l & 15, g = l >> 4;
    const int blk = blockIdx.x;
    const int tg = blk & 15;
    const int h = (blk >> 4) % NHEADS;
    const int b = blk / (16 * NHEADS);
    const int ti = (tg >> 2) * 16, tj = (tg & 3) * 16;
    const int pi0 = ti + w * 4;
    const int ws = min(max(pi0 - 3, 0), IMG_H - 10);
    const int cs = min(max(tj - 3, 0), IMG_W - 22);
    const int pixbase = b * 4096;

    unsigned short* Kl = smem + w * 5888;
    unsigned short* Vt = Kl + 2304;

    const int pj = tj + c15;
    const int sj = min(max(pj - 3, 0), IMG_W - KSZ);
    const unsigned int cm = 0x7Fu << (sj - cs);
    unsigned int rm[4];
    #pragma unroll
    for (int qt = 0; qt < 4; ++qt) {
        int si = min(max(pi0 + qt - 3, 0), IMG_H - KSZ);
        rm[qt] = 0x7Fu << (si - ws);
    }

    bf16x8 qf[4][2];
    #pragma unroll
    for (int qt = 0; qt < 4; ++qt)
        #pragma unroll
        for (int dh = 0; dh < 2; ++dh)
            qf[qt][dh] = *(const bf16x8*)(qkv +
                (size_t)(pixbase + (pi0 + qt) * 64 + tj + c15) * QKV_N + h * HDIM + dh * 32 + g * 8);

    const int sr = l & 31;
    const int h5 = l >> 5;
    const int sig = ((sr & 12) << 1) | ((sr & 16) >> 2) | (sr & 3);  // slot perm 8g+4t+j

    u16x8 kst[4], vst[4];

    {
        int ur = sr / 22, uc = sr - ur * 22;
        int prow = min(ws + ur, IMG_H - 1);
        const u16x8* gk = (const u16x8*)(qkv +
            (size_t)(pixbase + prow * 64 + cs + uc) * QKV_N + EMBED + h * HDIM + h5 * 32);
        #pragma unroll
        for (int i = 0; i < 4; ++i) { kst[i] = gk[i]; vst[i] = gk[i + 96]; }
    }
    #pragma unroll
    for (int i = 0; i < 4; ++i) *(u16x8*)(Kl + sr * 72 + h5 * 32 + i * 8) = kst[i];
    #pragma unroll
    for (int i = 0; i < 4; ++i)
        #pragma unroll
        for (int e = 0; e < 8; ++e)
            Vt[(h5 * 32 + i * 8 + e) * 56 + sig] = vst[i][e];

    f32x4 oacc[4][4] = {};
    float spart[4] = {0.f, 0.f, 0.f, 0.f};

    #pragma unroll 1
    for (int C = 0; C < 7; ++C) {
        if (C < 6) {
            int kk = (C + 1) * 32 + sr;
            int ur = kk / 22, uc = kk - ur * 22;
            int prow = min(ws + ur, IMG_H - 1);
            const u16x8* gk = (const u16x8*)(qkv +
                (size_t)(pixbase + prow * 64 + cs + uc) * QKV_N + EMBED + h * HDIM + h5 * 32);
            #pragma unroll
            for (int i = 0; i < 4; ++i) { kst[i] = gk[i]; vst[i] = gk[i + 96]; }
        }

        bf16x8 ka[2][2], vb[4];
        #pragma unroll
        for (int kt = 0; kt < 2; ++kt)
            #pragma unroll
            for (int dh = 0; dh < 2; ++dh)
                ka[kt][dh] = *(const bf16x8*)(Kl + (kt * 16 + c15) * 72 + dh * 32 + g * 8);
        #pragma unroll
        for (int dt = 0; dt < 4; ++dt)
            vb[dt] = *(const bf16x8*)(Vt + (dt * 16 + c15) * 56 + g * 8);

        int kk0 = C * 32 + 4 * g;
        int a22 = kk0 / 22;
        int uc0 = kk0 - a22 * 22;
        int urx[2][4]; unsigned int cb[2][4];
        #pragma unroll
        for (int kt = 0; kt < 2; ++kt)
            #pragma unroll
            for (int r = 0; r < 4; ++r) {
                int x = uc0 + kt * 16 + r;
                int wrp = x >= 22;
                int uc = x - (wrp ? 22 : 0);
                urx[kt][r] = a22 + wrp;
                cb[kt][r] = (cm >> uc) & 1u;
            }

        #pragma unroll
        for (int qt = 0; qt < 4; ++qt) {
            f32x4 s0 = {}, s1 = {};
            s0 = __builtin_amdgcn_mfma_f32_16x16x32_bf16(ka[0][0], qf[qt][0], s0, 0, 0, 0);
            s0 = __builtin_amdgcn_mfma_f32_16x16x32_bf16(ka[0][1], qf[qt][1], s0, 0, 0, 0);
            s1 = __builtin_amdgcn_mfma_f32_16x16x32_bf16(ka[1][0], qf[qt][0], s1, 0, 0, 0);
            s1 = __builtin_amdgcn_mfma_f32_16x16x32_bf16(ka[1][1], qf[qt][1], s1, 0, 0, 0);
            float p[2][4];
            #pragma unroll
            for (int r = 0; r < 4; ++r) {
                float e0 = exp2f(s0[r]);
                float e1 = exp2f(s1[r]);
                p[0][r] = ((rm[qt] >> urx[0][r]) & cb[0][r]) ? e0 : 0.f;
                p[1][r] = ((rm[qt] >> urx[1][r]) & cb[1][r]) ? e1 : 0.f;
                spart[qt] += p[0][r] + p[1][r];
            }
            unsigned int pk[4];
            asm("v_cvt_pk_bf16_f32 %0, %1, %2" : "=v"(pk[0]) : "v"(p[0][0]), "v"(p[0][1]));
            asm("v_cvt_pk_bf16_f32 %0, %1, %2" : "=v"(pk[1]) : "v"(p[0][2]), "v"(p[0][3]));
            asm("v_cvt_pk_bf16_f32 %0, %1, %2" : "=v"(pk[2]) : "v"(p[1][0]), "v"(p[1][1]));
            asm("v_cvt_pk_bf16_f32 %0, %1, %2" : "=v"(pk[3]) : "v"(p[1][2]), "v"(p[1][3]));
            bf16x8 pa = *(bf16x8*)pk;
            #pragma unroll
            for (int dt = 0; dt < 4; ++dt)
                oacc[qt][dt] = __builtin_amdgcn_mfma_f32_16x16x32_bf16(pa, vb[dt], oacc[qt][dt], 0, 0, 0);
        }

        if (C < 6) {
            #pragma unroll
            for (int i = 0; i < 4; ++i) *(u16x8*)(Kl + sr * 72 + h5 * 32 + i * 8) = kst[i];
            #pragma unroll
            for (int i = 0; i < 4; ++i)
                #pragma unroll
                for (int e = 0; e < 8; ++e)
                    Vt[(h5 * 32 + i * 8 + e) * 56 + sig] = vst[i][e];
        }
    }

    #pragma unroll
    for (int qt = 0; qt < 4; ++qt) {
        float s = spart[qt];
        s += __shfl_xor(s, 16);
        s += __shfl_xor(s, 32);
        #pragma unroll
        for (int r = 0; r < 4; ++r) {
            float sb = __shfl(s, 4 * g + r);
            float inv = __builtin_amdgcn_rcpf(sb);
            size_t obase = (size_t)(pixbase + (pi0 + qt) * 64 + tj + 4 * g + r) * EMBED
                         + h * HDIM + c15;
            #pragma unroll
            for (int dt = 0; dt < 4; ++dt)
                attn_bf[obase + dt * 16] = f2bf(oacc[qt][dt][r] * inv);
        }
    }
}

// ---------------- launch ----------------
extern "C" void kernel_launch(void* const* d_in, const int* in_sizes, int n_in,
                              void* d_out, int out_size, void* d_ws, size_t ws_size,
                              hipStream_t stream)
{
    const float* x      = (const float*)d_in[0];
    const float* w_qkv  = (const float*)d_in[1];
    const float* b_qkv  = (const float*)d_in[2];
    const float* w_proj = (const float*)d_in[3];
    const float* b_proj = (const float*)d_in[4];
    float* out = (float*)d_out;

    // workspace (~206 MB)
    char* p = (char*)d_ws;
    unsigned short* qkv = (unsigned short*)p;     p += (size_t)NTOK * QKV_N * 2;       // 151 MB
    unsigned short* xbf = (unsigned short*)p;     // aliased: x_bf then attn_bf
    unsigned short* attn_bf = xbf;                p += (size_t)NTOK * EMBED * 2;       // 50 MB
    unsigned short* wq_bf = (unsigned short*)p;   p += (size_t)QKV_N * EMBED * 2;      // 3.5 MB
    unsigned short* wp_bf = (unsigned short*)p;

    const float scale = 0.125f * 1.44269504088896f;  // HDIM^-0.5 * log2(e)

    {
        int n4 = NTOK * EMBED / 4;
        cvt_bf16_kernel<<<(n4 + 255) / 256, 256, 0, stream>>>(x, xbf, n4);
        n4 = QKV_N * EMBED / 4;
        cvt_bf16_kernel<<<(n4 + 255) / 256, 256, 0, stream>>>(w_qkv, wq_bf, n4);
        n4 = EMBED * EMBED / 4;
        cvt_bf16_kernel<<<(n4 + 255) / 256, 256, 0, stream>>>(w_proj, wp_bf, n4);
    }

    {
        // GEMM1: M=32768, N=2304 -> 256 x 18 = 4608 blocks (nwg % 8 == 0)
        gemm128<1><<<(NTOK / 128) * (QKV_N / 128), 256, 0, stream>>>(
            xbf, wq_bf, b_qkv, qkv, NTOK, QKV_N, EMBED, EMBED, scale);
    }

    natten_kernel<<<BATCH * NHEADS * 16, 256, 0, stream>>>(qkv, attn_bf);

    {
        // GEMM2: M=32768, N=768 -> 256 x 6 = 1536 blocks (nwg % 8 == 0)
        gemm128<0><<<(NTOK / 128) * (EMBED / 128), 256, 0, stream>>>(
            attn_bf, wp_bf, b_proj, out, NTOK, EMBED, EMBED, 0, 1.0f);
    }
}

// Round 9
// 325.925 us; speedup vs baseline: 1.6142x; 1.1242x over previous
//
#include <hip/hip_runtime.h>
#include <cstddef>

#define EMBED   768
#define NHEADS  12
#define HDIM    64
#define KSZ     7
#define IMG_H   64
#define IMG_W   64
#define BATCH   8
#define NTOK    (BATCH*IMG_H*IMG_W)   /* 32768 */
#define QKV_N   (3*EMBED)             /* 2304  */

typedef __attribute__((ext_vector_type(8))) short  bf16x8;
typedef __attribute__((ext_vector_type(4))) float  f32x4;
typedef __attribute__((ext_vector_type(8))) unsigned short u16x8;
typedef __attribute__((ext_vector_type(4))) unsigned short u16x4;

__device__ __forceinline__ unsigned short f2bf(float f) {
    unsigned int u = __float_as_uint(f);
    u += 0x7FFFu + ((u >> 16) & 1u);      // RNE
    return (unsigned short)(u >> 16);
}

__device__ __forceinline__ void gload_lds16(const void* g, void* l) {
    __builtin_amdgcn_global_load_lds(
        (const __attribute__((address_space(1))) unsigned int*)g,
        (__attribute__((address_space(3))) unsigned int*)l, 16, 0, 0);
}

// ---------------- fp32 -> bf16 conversion ----------------
__global__ __launch_bounds__(256)
void cvt_bf16_kernel(const float* __restrict__ in, unsigned short* __restrict__ out, int n4)
{
    int i = blockIdx.x * 256 + threadIdx.x;
    if (i < n4) {
        float4 f = *(const float4*)(in + (size_t)i * 4);
        u16x4 o;
        o[0] = f2bf(f.x); o[1] = f2bf(f.y); o[2] = f2bf(f.z); o[3] = f2bf(f.w);
        *(u16x4*)(out + (size_t)i * 4) = o;
    }
}

// ---------------- bf16 MFMA GEMM v6: 256x256, BK=64, 8 waves, 4-phase counted pipeline ----
// Wave (wm=w>>2, wn=w&3) owns 128x64 out: 8 m-frags x 4 n-frags of 16x16x32.
// LDS: 2 buffers x (A 32KB + B 32KB) = 128 KB. Subtile (16 rows x 32 k) = 1KB,
// fragment-linear + slot-permuted (proven 0 bank conflicts, rounds 6/8):
//   gload writes lane-linear (lane*16B); per-lane GLOBAL src row = l>>2 (quad-coalesced
//   64B), kchunk = (l&3)^((l>>3)&3); ds_read lane l: row l&15, slot (l>>4)^((l>>1)&3).
// Half-tiles are K-halves (kk in {0,1}): A-kh(kk) = 16 subtiles (all 256 rows), B same.
// Phase q of tile t: {ds_read this phase's frags; stage 1 half of tile t+1;
//   [vmcnt(4) at ends of q1/q3 -- counted, FIFO-exact]; s_barrier(asm, no drain);
//   setprio(1); 16 MFMA; setprio(0)}.
// FIFO math: stages/tile = 4 halves x 2 loads = 8/thread. At q1-end the queue is
// [A1(t),B1(t),A0(t+1),B0(t+1)] = 8 -> vmcnt(4) retires kh1(t) (needed by q2/q3 reads).
// At q3-end: [A0..B1](t+1) = 8 -> vmcnt(4) retires kh0(t+1) (needed by next q0/q1).
// Reads in phase p are validated by the barrier ending phase p-1; DMA overwrite of a
// buffer trails its last reader by >= 2 barriers. Never vmcnt(0) except the last tile.
template<int BF16OUT>
__global__ __launch_bounds__(512)
void gemm256(const unsigned short* __restrict__ A, const unsigned short* __restrict__ W,
             const float* __restrict__ bias, void* __restrict__ outp,
             int M, int N, int K, int scaleN, float scale)
{
    __shared__ unsigned short lds[65536];   // 128 KiB: buf c at c (ushorts), B at +16384
    const int t_ = threadIdx.x;
    const int l = t_ & 63, w = t_ >> 6;
    const int wm = w >> 2, wn = w & 3;

    // XCD swizzle (nwg % 8 == 0 for both GEMMs)
    const int nbx = M >> 8;
    const int cpx = gridDim.x >> 3;
    const int lin = blockIdx.x;
    const int swz = (lin & 7) * cpx + (lin >> 3);
    const int bm = (swz % nbx) << 8;
    const int bn = (swz / nbx) << 8;

    // staging source (quad-coalesced, slot-permuted); wave w stages m16 = 2w (+1 via rstep)
    const int kperm8 = ((l & 3) ^ ((l >> 3) & 3)) * 8;
    const unsigned short* gA = A + (size_t)(bm + 2 * w * 16 + (l >> 2)) * K + kperm8;
    const unsigned short* gB = W + (size_t)(bn + 2 * w * 16 + (l >> 2)) * K + kperm8;
    const size_t rstep = (size_t)16 * K;

    const int dA = w * 2048;               // stage dst base: sub (4w+2j+kk)*512
    const int foff = (l & 15) * 32 + (((l >> 4) ^ ((l >> 1) & 3)) * 8);
    const int aoff = wm * 8192;            // + (m*2+kk)*512
    const int boff = 16384 + wn * 4096;    // + (n*2+kk)*512

    f32x4 acc[8][4] = {};
    const int NT = K / 64;                 // 12

#define BARRIER() asm volatile("s_barrier" ::: "memory")
#define WAITV4()  asm volatile("s_waitcnt vmcnt(4)" ::: "memory")
#define WAITV0()  asm volatile("s_waitcnt vmcnt(0)" ::: "memory")
#define STGA(c, k0, kk) do { \
        gload_lds16(gA + (size_t)(k0) + (kk) * 32,         lds + (c) + dA + (kk) * 512); \
        gload_lds16(gA + rstep + (size_t)(k0) + (kk) * 32, lds + (c) + dA + (2 + (kk)) * 512); } while (0)
#define STGB(c, k0, kk) do { \
        gload_lds16(gB + (size_t)(k0) + (kk) * 32,         lds + (c) + 16384 + dA + (kk) * 512); \
        gload_lds16(gB + rstep + (size_t)(k0) + (kk) * 32, lds + (c) + 16384 + dA + (2 + (kk)) * 512); } while (0)

    // prologue: stage tile 0 in FIFO order A0,B0,A1,B1; retire kh0
    STGA(0, 0, 0); STGB(0, 0, 0); STGA(0, 0, 1); STGB(0, 0, 1);
    WAITV4();
    BARRIER();

    for (int t = 0; t < NT; ++t) {
        const int c  = (t & 1) << 15;
        const int cn = c ^ 32768;
        const int k1 = (t + 1) * 64;
        const bool pf = (t + 1) < NT;

        bf16x8 a[4], bq[4];

        // ---- phase 0: kk0, m0-3 (8 ds_read) ----
        #pragma unroll
        for (int m = 0; m < 4; ++m) a[m]  = *(const bf16x8*)(lds + c + aoff + (m * 2) * 512 + foff);
        #pragma unroll
        for (int n = 0; n < 4; ++n) bq[n] = *(const bf16x8*)(lds + c + boff + (n * 2) * 512 + foff);
        if (pf) STGA(cn, k1, 0);
        BARRIER();
        __builtin_amdgcn_s_setprio(1);
        #pragma unroll
        for (int m = 0; m < 4; ++m)
            #pragma unroll
            for (int n = 0; n < 4; ++n)
                acc[m][n] = __builtin_amdgcn_mfma_f32_16x16x32_bf16(a[m], bq[n], acc[m][n], 0, 0, 0);
        __builtin_amdgcn_s_setprio(0);

        // ---- phase 1: kk0, m4-7 (4 ds_read, B reused) ----
        #pragma unroll
        for (int m = 0; m < 4; ++m) a[m] = *(const bf16x8*)(lds + c + aoff + ((4 + m) * 2) * 512 + foff);
        if (pf) { STGB(cn, k1, 0); WAITV4(); } else { WAITV0(); }
        BARRIER();
        __builtin_amdgcn_s_setprio(1);
        #pragma unroll
        for (int m = 0; m < 4; ++m)
            #pragma unroll
            for (int n = 0; n < 4; ++n)
                acc[4 + m][n] = __builtin_amdgcn_mfma_f32_16x16x32_bf16(a[m], bq[n], acc[4 + m][n], 0, 0, 0);
        __builtin_amdgcn_s_setprio(0);

        // ---- phase 2: kk1, m0-3 (8 ds_read) ----
        #pragma unroll
        for (int m = 0; m < 4; ++m) a[m]  = *(const bf16x8*)(lds + c + aoff + (m * 2 + 1) * 512 + foff);
        #pragma unroll
        for (int n = 0; n < 4; ++n) bq[n] = *(const bf16x8*)(lds + c + boff + (n * 2 + 1) * 512 + foff);
        if (pf) STGA(cn, k1, 1);
        BARRIER();
        __builtin_amdgcn_s_setprio(1);
        #pragma unroll
        for (int m = 0; m < 4; ++m)
            #pragma unroll
            for (int n = 0; n < 4; ++n)
                acc[m][n] = __builtin_amdgcn_mfma_f32_16x16x32_bf16(a[m], bq[n], acc[m][n], 0, 0, 0);
        __builtin_amdgcn_s_setprio(0);

        // ---- phase 3: kk1, m4-7 (4 ds_read) ----
        #pragma unroll
        for (int m = 0; m < 4; ++m) a[m] = *(const bf16x8*)(lds + c + aoff + ((4 + m) * 2 + 1) * 512 + foff);
        if (pf) { STGB(cn, k1, 1); WAITV4(); }
        BARRIER();
        __builtin_amdgcn_s_setprio(1);
        #pragma unroll
        for (int m = 0; m < 4; ++m)
            #pragma unroll
            for (int n = 0; n < 4; ++n)
                acc[4 + m][n] = __builtin_amdgcn_mfma_f32_16x16x32_bf16(a[m], bq[n], acc[4 + m][n], 0, 0, 0);
        __builtin_amdgcn_s_setprio(0);
    }
#undef BARRIER
#undef WAITV4
#undef WAITV0
#undef STGA
#undef STGB

    // ---- scalar epilogue (proven write-combining: WRITE_SIZE == data size) ----
    const int cr = (l >> 4) * 4;
    const int cc = l & 15;
    #pragma unroll
    for (int m = 0; m < 8; ++m) {
        #pragma unroll
        for (int n = 0; n < 4; ++n) {
            const int col = bn + wn * 64 + n * 16 + cc;
            const float bv = bias[col];
            const bool sc = col < scaleN;
            #pragma unroll
            for (int r = 0; r < 4; ++r) {
                const int row = bm + wm * 128 + m * 16 + cr + r;
                float v = acc[m][n][r] + bv;
                if (sc) v *= scale;
                if (BF16OUT) ((unsigned short*)outp)[(size_t)row * N + col] = f2bf(v);
                else         ((float*)outp)[(size_t)row * N + col] = v;
            }
        }
    }
}

// ---------------- MFMA neighborhood attention (verified round 4) ----------------
__global__ __launch_bounds__(256)
void natten_kernel(const unsigned short* __restrict__ qkv, unsigned short* __restrict__ attn_bf)
{
    __shared__ unsigned short smem[4 * 5888];   // per wave: K 32x72 + V^T 64x56
    const int t = threadIdx.x;
    const int w = t >> 6, l = t & 63;
    const int c15 = l & 15, g = l >> 4;
    const int blk = blockIdx.x;
    const int tg = blk & 15;
    const int h = (blk >> 4) % NHEADS;
    const int b = blk / (16 * NHEADS);
    const int ti = (tg >> 2) * 16, tj = (tg & 3) * 16;
    const int pi0 = ti + w * 4;
    const int ws = min(max(pi0 - 3, 0), IMG_H - 10);
    const int cs = min(max(tj - 3, 0), IMG_W - 22);
    const int pixbase = b * 4096;

    unsigned short* Kl = smem + w * 5888;
    unsigned short* Vt = Kl + 2304;

    const int pj = tj + c15;
    const int sj = min(max(pj - 3, 0), IMG_W - KSZ);
    const unsigned int cm = 0x7Fu << (sj - cs);
    unsigned int rm[4];
    #pragma unroll
    for (int qt = 0; qt < 4; ++qt) {
        int si = min(max(pi0 + qt - 3, 0), IMG_H - KSZ);
        rm[qt] = 0x7Fu << (si - ws);
    }

    bf16x8 qf[4][2];
    #pragma unroll
    for (int qt = 0; qt < 4; ++qt)
        #pragma unroll
        for (int dh = 0; dh < 2; ++dh)
            qf[qt][dh] = *(const bf16x8*)(qkv +
                (size_t)(pixbase + (pi0 + qt) * 64 + tj + c15) * QKV_N + h * HDIM + dh * 32 + g * 8);

    const int sr = l & 31;
    const int h5 = l >> 5;
    const int sig = ((sr & 12) << 1) | ((sr & 16) >> 2) | (sr & 3);  // slot perm 8g+4t+j

    u16x8 kst[4], vst[4];

    {
        int ur = sr / 22, uc = sr - ur * 22;
        int prow = min(ws + ur, IMG_H - 1);
        const u16x8* gk = (const u16x8*)(qkv +
            (size_t)(pixbase + prow * 64 + cs + uc) * QKV_N + EMBED + h * HDIM + h5 * 32);
        #pragma unroll
        for (int i = 0; i < 4; ++i) { kst[i] = gk[i]; vst[i] = gk[i + 96]; }
    }
    #pragma unroll
    for (int i = 0; i < 4; ++i) *(u16x8*)(Kl + sr * 72 + h5 * 32 + i * 8) = kst[i];
    #pragma unroll
    for (int i = 0; i < 4; ++i)
        #pragma unroll
        for (int e = 0; e < 8; ++e)
            Vt[(h5 * 32 + i * 8 + e) * 56 + sig] = vst[i][e];

    f32x4 oacc[4][4] = {};
    float spart[4] = {0.f, 0.f, 0.f, 0.f};

    #pragma unroll 1
    for (int C = 0; C < 7; ++C) {
        if (C < 6) {
            int kk = (C + 1) * 32 + sr;
            int ur = kk / 22, uc = kk - ur * 22;
            int prow = min(ws + ur, IMG_H - 1);
            const u16x8* gk = (const u16x8*)(qkv +
                (size_t)(pixbase + prow * 64 + cs + uc) * QKV_N + EMBED + h * HDIM + h5 * 32);
            #pragma unroll
            for (int i = 0; i < 4; ++i) { kst[i] = gk[i]; vst[i] = gk[i + 96]; }
        }

        bf16x8 ka[2][2], vb[4];
        #pragma unroll
        for (int kt = 0; kt < 2; ++kt)
            #pragma unroll
            for (int dh = 0; dh < 2; ++dh)
                ka[kt][dh] = *(const bf16x8*)(Kl + (kt * 16 + c15) * 72 + dh * 32 + g * 8);
        #pragma unroll
        for (int dt = 0; dt < 4; ++dt)
            vb[dt] = *(const bf16x8*)(Vt + (dt * 16 + c15) * 56 + g * 8);

        int kk0 = C * 32 + 4 * g;
        int a22 = kk0 / 22;
        int uc0 = kk0 - a22 * 22;
        int urx[2][4]; unsigned int cb[2][4];
        #pragma unroll
        for (int kt = 0; kt < 2; ++kt)
            #pragma unroll
            for (int r = 0; r < 4; ++r) {
                int x = uc0 + kt * 16 + r;
                int wrp = x >= 22;
                int uc = x - (wrp ? 22 : 0);
                urx[kt][r] = a22 + wrp;
                cb[kt][r] = (cm >> uc) & 1u;
            }

        #pragma unroll
        for (int qt = 0; qt < 4; ++qt) {
            f32x4 s0 = {}, s1 = {};
            s0 = __builtin_amdgcn_mfma_f32_16x16x32_bf16(ka[0][0], qf[qt][0], s0, 0, 0, 0);
            s0 = __builtin_amdgcn_mfma_f32_16x16x32_bf16(ka[0][1], qf[qt][1], s0, 0, 0, 0);
            s1 = __builtin_amdgcn_mfma_f32_16x16x32_bf16(ka[1][0], qf[qt][0], s1, 0, 0, 0);
            s1 = __builtin_amdgcn_mfma_f32_16x16x32_bf16(ka[1][1], qf[qt][1], s1, 0, 0, 0);
            float p[2][4];
            #pragma unroll
            for (int r = 0; r < 4; ++r) {
                float e0 = exp2f(s0[r]);
                float e1 = exp2f(s1[r]);
                p[0][r] = ((rm[qt] >> urx[0][r]) & cb[0][r]) ? e0 : 0.f;
                p[1][r] = ((rm[qt] >> urx[1][r]) & cb[1][r]) ? e1 : 0.f;
                spart[qt] += p[0][r] + p[1][r];
            }
            unsigned int pk[4];
            asm("v_cvt_pk_bf16_f32 %0, %1, %2" : "=v"(pk[0]) : "v"(p[0][0]), "v"(p[0][1]));
            asm("v_cvt_pk_bf16_f32 %0, %1, %2" : "=v"(pk[1]) : "v"(p[0][2]), "v"(p[0][3]));
            asm("v_cvt_pk_bf16_f32 %0, %1, %2" : "=v"(pk[2]) : "v"(p[1][0]), "v"(p[1][1]));
            asm("v_cvt_pk_bf16_f32 %0, %1, %2" : "=v"(pk[3]) : "v"(p[1][2]), "v"(p[1][3]));
            bf16x8 pa = *(bf16x8*)pk;
            #pragma unroll
            for (int dt = 0; dt < 4; ++dt)
                oacc[qt][dt] = __builtin_amdgcn_mfma_f32_16x16x32_bf16(pa, vb[dt], oacc[qt][dt], 0, 0, 0);
        }

        if (C < 6) {
            #pragma unroll
            for (int i = 0; i < 4; ++i) *(u16x8*)(Kl + sr * 72 + h5 * 32 + i * 8) = kst[i];
            #pragma unroll
            for (int i = 0; i < 4; ++i)
                #pragma unroll
                for (int e = 0; e < 8; ++e)
                    Vt[(h5 * 32 + i * 8 + e) * 56 + sig] = vst[i][e];
        }
    }

    #pragma unroll
    for (int qt = 0; qt < 4; ++qt) {
        float s = spart[qt];
        s += __shfl_xor(s, 16);
        s += __shfl_xor(s, 32);
        #pragma unroll
        for (int r = 0; r < 4; ++r) {
            float sb = __shfl(s, 4 * g + r);
            float inv = __builtin_amdgcn_rcpf(sb);
            size_t obase = (size_t)(pixbase + (pi0 + qt) * 64 + tj + 4 * g + r) * EMBED
                         + h * HDIM + c15;
            #pragma unroll
            for (int dt = 0; dt < 4; ++dt)
                attn_bf[obase + dt * 16] = f2bf(oacc[qt][dt][r] * inv);
        }
    }
}

// ---------------- launch ----------------
extern "C" void kernel_launch(void* const* d_in, const int* in_sizes, int n_in,
                              void* d_out, int out_size, void* d_ws, size_t ws_size,
                              hipStream_t stream)
{
    const float* x      = (const float*)d_in[0];
    const float* w_qkv  = (const float*)d_in[1];
    const float* b_qkv  = (const float*)d_in[2];
    const float* w_proj = (const float*)d_in[3];
    const float* b_proj = (const float*)d_in[4];
    float* out = (float*)d_out;

    // workspace (~206 MB)
    char* p = (char*)d_ws;
    unsigned short* qkv = (unsigned short*)p;     p += (size_t)NTOK * QKV_N * 2;       // 151 MB
    unsigned short* xbf = (unsigned short*)p;     // aliased: x_bf then attn_bf
    unsigned short* attn_bf = xbf;                p += (size_t)NTOK * EMBED * 2;       // 50 MB
    unsigned short* wq_bf = (unsigned short*)p;   p += (size_t)QKV_N * EMBED * 2;      // 3.5 MB
    unsigned short* wp_bf = (unsigned short*)p;

    const float scale = 0.125f * 1.44269504088896f;  // HDIM^-0.5 * log2(e)

    {
        int n4 = NTOK * EMBED / 4;
        cvt_bf16_kernel<<<(n4 + 255) / 256, 256, 0, stream>>>(x, xbf, n4);
        n4 = QKV_N * EMBED / 4;
        cvt_bf16_kernel<<<(n4 + 255) / 256, 256, 0, stream>>>(w_qkv, wq_bf, n4);
        n4 = EMBED * EMBED / 4;
        cvt_bf16_kernel<<<(n4 + 255) / 256, 256, 0, stream>>>(w_proj, wp_bf, n4);
    }

    {
        // GEMM1: M=32768, N=2304 -> 128 x 9 = 1152 blocks (nwg % 8 == 0)
        gemm256<1><<<(NTOK / 256) * (QKV_N / 256), 512, 0, stream>>>(
            xbf, wq_bf, b_qkv, qkv, NTOK, QKV_N, EMBED, EMBED, scale);
    }

    natten_kernel<<<BATCH * NHEADS * 16, 256, 0, stream>>>(qkv, attn_bf);

    {
        // GEMM2: M=32768, N=768 -> 128 x 3 = 384 blocks (nwg % 8 == 0)
        gemm256<0><<<(NTOK / 256) * (EMBED / 256), 512, 0, stream>>>(
            attn_bf, wp_bf, b_proj, out, NTOK, EMBED, EMBED, 0, 1.0f);
    }
}

// Round 10
// 321.912 us; speedup vs baseline: 1.6343x; 1.0125x over previous
//
#include <hip/hip_runtime.h>
#include <cstddef>

#define EMBED   768
#define NHEADS  12
#define HDIM    64
#define KSZ     7
#define IMG_H   64
#define IMG_W   64
#define BATCH   8
#define NTOK    (BATCH*IMG_H*IMG_W)   /* 32768 */
#define QKV_N   (3*EMBED)             /* 2304  */

typedef __attribute__((ext_vector_type(8))) short  bf16x8;
typedef __attribute__((ext_vector_type(4))) float  f32x4;
typedef __attribute__((ext_vector_type(8))) unsigned short u16x8;
typedef __attribute__((ext_vector_type(4))) unsigned short u16x4;

__device__ __forceinline__ unsigned short f2bf(float f) {
    unsigned int u = __float_as_uint(f);
    u += 0x7FFFu + ((u >> 16) & 1u);      // RNE
    return (unsigned short)(u >> 16);
}

__device__ __forceinline__ void gload_lds16(const void* g, void* l) {
    __builtin_amdgcn_global_load_lds(
        (const __attribute__((address_space(1))) unsigned int*)g,
        (__attribute__((address_space(3))) unsigned int*)l, 16, 0, 0);
}

// ---------------- fp32 -> bf16 conversion ----------------
__global__ __launch_bounds__(256)
void cvt_bf16_kernel(const float* __restrict__ in, unsigned short* __restrict__ out, int n4)
{
    int i = blockIdx.x * 256 + threadIdx.x;
    if (i < n4) {
        float4 f = *(const float4*)(in + (size_t)i * 4);
        u16x4 o;
        o[0] = f2bf(f.x); o[1] = f2bf(f.y); o[2] = f2bf(f.z); o[3] = f2bf(f.w);
        *(u16x4*)(out + (size_t)i * 4) = o;
    }
}

// ---------------- bf16 MFMA GEMM v7: v6 schedule + bn-fastest XCD block order ----------
// v6 (round 9, proven 146us/GEMM1, 0 conflicts, race-free): 256x256, BK=64, 8 waves,
// 2x64KB LDS, 4-phase counted vmcnt(4), fragment-linear slot-permuted LDS.
// v7 change (ONLY): block->tile mapping. Within each XCD (xcd = blockIdx.x & 7,
// round-robin dispatch): 16 bm-groups x nby bn-blocks, bn INNERMOST + serpentine.
// Working set/XCD = 1 A-block (393KB, hot across its nby visits) + B panel
// (nby*393KB <= 3.5MB, L2-resident) -> A fetched ~once, B ~once per XCD.
template<int BF16OUT>
__global__ __launch_bounds__(512)
void gemm256(const unsigned short* __restrict__ A, const unsigned short* __restrict__ W,
             const float* __restrict__ bias, void* __restrict__ outp,
             int M, int N, int K, int scaleN, float scale)
{
    __shared__ unsigned short lds[65536];   // 128 KiB: buf c at c (ushorts), B at +16384
    const int t_ = threadIdx.x;
    const int l = t_ & 63, w = t_ >> 6;
    const int wm = w >> 2, wn = w & 3;

    // bn-fastest serpentine mapping within XCD
    const int nby = N >> 8;
    const int xcd = blockIdx.x & 7;
    const int loc = blockIdx.x >> 3;
    const int bmg = loc / nby;
    int bnq = loc - bmg * nby;
    if (bmg & 1) bnq = nby - 1 - bnq;
    const int bm = (xcd * (((M >> 8) >> 3)) + bmg) << 8;
    const int bn = bnq << 8;

    // staging source (quad-coalesced, slot-permuted); wave w stages m16 = 2w (+1 via rstep)
    const int kperm8 = ((l & 3) ^ ((l >> 3) & 3)) * 8;
    const unsigned short* gA = A + (size_t)(bm + 2 * w * 16 + (l >> 2)) * K + kperm8;
    const unsigned short* gB = W + (size_t)(bn + 2 * w * 16 + (l >> 2)) * K + kperm8;
    const size_t rstep = (size_t)16 * K;

    const int dA = w * 2048;               // stage dst base: sub (4w+2j+kk)*512
    const int foff = (l & 15) * 32 + (((l >> 4) ^ ((l >> 1) & 3)) * 8);
    const int aoff = wm * 8192;            // + (m*2+kk)*512
    const int boff = 16384 + wn * 4096;    // + (n*2+kk)*512

    f32x4 acc[8][4] = {};
    const int NT = K / 64;                 // 12

#define BARRIER() asm volatile("s_barrier" ::: "memory")
#define WAITV4()  asm volatile("s_waitcnt vmcnt(4)" ::: "memory")
#define WAITV0()  asm volatile("s_waitcnt vmcnt(0)" ::: "memory")
#define STGA(c, k0, kk) do { \
        gload_lds16(gA + (size_t)(k0) + (kk) * 32,         lds + (c) + dA + (kk) * 512); \
        gload_lds16(gA + rstep + (size_t)(k0) + (kk) * 32, lds + (c) + dA + (2 + (kk)) * 512); } while (0)
#define STGB(c, k0, kk) do { \
        gload_lds16(gB + (size_t)(k0) + (kk) * 32,         lds + (c) + 16384 + dA + (kk) * 512); \
        gload_lds16(gB + rstep + (size_t)(k0) + (kk) * 32, lds + (c) + 16384 + dA + (2 + (kk)) * 512); } while (0)

    // prologue: stage tile 0 in FIFO order A0,B0,A1,B1; retire kh0
    STGA(0, 0, 0); STGB(0, 0, 0); STGA(0, 0, 1); STGB(0, 0, 1);
    WAITV4();
    BARRIER();

    for (int t = 0; t < NT; ++t) {
        const int c  = (t & 1) << 15;
        const int cn = c ^ 32768;
        const int k1 = (t + 1) * 64;
        const bool pf = (t + 1) < NT;

        bf16x8 a[4], bq[4];

        // ---- phase 0: kk0, m0-3 (8 ds_read) ----
        #pragma unroll
        for (int m = 0; m < 4; ++m) a[m]  = *(const bf16x8*)(lds + c + aoff + (m * 2) * 512 + foff);
        #pragma unroll
        for (int n = 0; n < 4; ++n) bq[n] = *(const bf16x8*)(lds + c + boff + (n * 2) * 512 + foff);
        if (pf) STGA(cn, k1, 0);
        BARRIER();
        __builtin_amdgcn_s_setprio(1);
        #pragma unroll
        for (int m = 0; m < 4; ++m)
            #pragma unroll
            for (int n = 0; n < 4; ++n)
                acc[m][n] = __builtin_amdgcn_mfma_f32_16x16x32_bf16(a[m], bq[n], acc[m][n], 0, 0, 0);
        __builtin_amdgcn_s_setprio(0);

        // ---- phase 1: kk0, m4-7 (4 ds_read, B reused) ----
        #pragma unroll
        for (int m = 0; m < 4; ++m) a[m] = *(const bf16x8*)(lds + c + aoff + ((4 + m) * 2) * 512 + foff);
        if (pf) { STGB(cn, k1, 0); WAITV4(); } else { WAITV0(); }
        BARRIER();
        __builtin_amdgcn_s_setprio(1);
        #pragma unroll
        for (int m = 0; m < 4; ++m)
            #pragma unroll
            for (int n = 0; n < 4; ++n)
                acc[4 + m][n] = __builtin_amdgcn_mfma_f32_16x16x32_bf16(a[m], bq[n], acc[4 + m][n], 0, 0, 0);
        __builtin_amdgcn_s_setprio(0);

        // ---- phase 2: kk1, m0-3 (8 ds_read) ----
        #pragma unroll
        for (int m = 0; m < 4; ++m) a[m]  = *(const bf16x8*)(lds + c + aoff + (m * 2 + 1) * 512 + foff);
        #pragma unroll
        for (int n = 0; n < 4; ++n) bq[n] = *(const bf16x8*)(lds + c + boff + (n * 2 + 1) * 512 + foff);
        if (pf) STGA(cn, k1, 1);
        BARRIER();
        __builtin_amdgcn_s_setprio(1);
        #pragma unroll
        for (int m = 0; m < 4; ++m)
            #pragma unroll
            for (int n = 0; n < 4; ++n)
                acc[m][n] = __builtin_amdgcn_mfma_f32_16x16x32_bf16(a[m], bq[n], acc[m][n], 0, 0, 0);
        __builtin_amdgcn_s_setprio(0);

        // ---- phase 3: kk1, m4-7 (4 ds_read) ----
        #pragma unroll
        for (int m = 0; m < 4; ++m) a[m] = *(const bf16x8*)(lds + c + aoff + ((4 + m) * 2 + 1) * 512 + foff);
        if (pf) { STGB(cn, k1, 1); WAITV4(); }
        BARRIER();
        __builtin_amdgcn_s_setprio(1);
        #pragma unroll
        for (int m = 0; m < 4; ++m)
            #pragma unroll
            for (int n = 0; n < 4; ++n)
                acc[4 + m][n] = __builtin_amdgcn_mfma_f32_16x16x32_bf16(a[m], bq[n], acc[4 + m][n], 0, 0, 0);
        __builtin_amdgcn_s_setprio(0);
    }
#undef BARRIER
#undef WAITV4
#undef WAITV0
#undef STGA
#undef STGB

    // ---- scalar epilogue (proven write-combining: WRITE_SIZE == data size) ----
    const int cr = (l >> 4) * 4;
    const int cc = l & 15;
    #pragma unroll
    for (int m = 0; m < 8; ++m) {
        #pragma unroll
        for (int n = 0; n < 4; ++n) {
            const int col = bn + wn * 64 + n * 16 + cc;
            const float bv = bias[col];
            const bool sc = col < scaleN;
            #pragma unroll
            for (int r = 0; r < 4; ++r) {
                const int row = bm + wm * 128 + m * 16 + cr + r;
                float v = acc[m][n][r] + bv;
                if (sc) v *= scale;
                if (BF16OUT) ((unsigned short*)outp)[(size_t)row * N + col] = f2bf(v);
                else         ((float*)outp)[(size_t)row * N + col] = v;
            }
        }
    }
}

// ---------------- MFMA neighborhood attention (verified round 4) ----------------
__global__ __launch_bounds__(256)
void natten_kernel(const unsigned short* __restrict__ qkv, unsigned short* __restrict__ attn_bf)
{
    __shared__ unsigned short smem[4 * 5888];   // per wave: K 32x72 + V^T 64x56
    const int t = threadIdx.x;
    const int w = t >> 6, l = t & 63;
    const int c15 = l & 15, g = l >> 4;
    const int blk = blockIdx.x;
    const int tg = blk & 15;
    const int h = (blk >> 4) % NHEADS;
    const int b = blk / (16 * NHEADS);
    const int ti = (tg >> 2) * 16, tj = (tg & 3) * 16;
    const int pi0 = ti + w * 4;
    const int ws = min(max(pi0 - 3, 0), IMG_H - 10);
    const int cs = min(max(tj - 3, 0), IMG_W - 22);
    const int pixbase = b * 4096;

    unsigned short* Kl = smem + w * 5888;
    unsigned short* Vt = Kl + 2304;

    const int pj = tj + c15;
    const int sj = min(max(pj - 3, 0), IMG_W - KSZ);
    const unsigned int cm = 0x7Fu << (sj - cs);
    unsigned int rm[4];
    #pragma unroll
    for (int qt = 0; qt < 4; ++qt) {
        int si = min(max(pi0 + qt - 3, 0), IMG_H - KSZ);
        rm[qt] = 0x7Fu << (si - ws);
    }

    bf16x8 qf[4][2];
    #pragma unroll
    for (int qt = 0; qt < 4; ++qt)
        #pragma unroll
        for (int dh = 0; dh < 2; ++dh)
            qf[qt][dh] = *(const bf16x8*)(qkv +
                (size_t)(pixbase + (pi0 + qt) * 64 + tj + c15) * QKV_N + h * HDIM + dh * 32 + g * 8);

    const int sr = l & 31;
    const int h5 = l >> 5;
    const int sig = ((sr & 12) << 1) | ((sr & 16) >> 2) | (sr & 3);  // slot perm 8g+4t+j

    u16x8 kst[4], vst[4];

    {
        int ur = sr / 22, uc = sr - ur * 22;
        int prow = min(ws + ur, IMG_H - 1);
        const u16x8* gk = (const u16x8*)(qkv +
            (size_t)(pixbase + prow * 64 + cs + uc) * QKV_N + EMBED + h * HDIM + h5 * 32);
        #pragma unroll
        for (int i = 0; i < 4; ++i) { kst[i] = gk[i]; vst[i] = gk[i + 96]; }
    }
    #pragma unroll
    for (int i = 0; i < 4; ++i) *(u16x8*)(Kl + sr * 72 + h5 * 32 + i * 8) = kst[i];
    #pragma unroll
    for (int i = 0; i < 4; ++i)
        #pragma unroll
        for (int e = 0; e < 8; ++e)
            Vt[(h5 * 32 + i * 8 + e) * 56 + sig] = vst[i][e];

    f32x4 oacc[4][4] = {};
    float spart[4] = {0.f, 0.f, 0.f, 0.f};

    #pragma unroll 1
    for (int C = 0; C < 7; ++C) {
        if (C < 6) {
            int kk = (C + 1) * 32 + sr;
            int ur = kk / 22, uc = kk - ur * 22;
            int prow = min(ws + ur, IMG_H - 1);
            const u16x8* gk = (const u16x8*)(qkv +
                (size_t)(pixbase + prow * 64 + cs + uc) * QKV_N + EMBED + h * HDIM + h5 * 32);
            #pragma unroll
            for (int i = 0; i < 4; ++i) { kst[i] = gk[i]; vst[i] = gk[i + 96]; }
        }

        bf16x8 ka[2][2], vb[4];
        #pragma unroll
        for (int kt = 0; kt < 2; ++kt)
            #pragma unroll
            for (int dh = 0; dh < 2; ++dh)
                ka[kt][dh] = *(const bf16x8*)(Kl + (kt * 16 + c15) * 72 + dh * 32 + g * 8);
        #pragma unroll
        for (int dt = 0; dt < 4; ++dt)
            vb[dt] = *(const bf16x8*)(Vt + (dt * 16 + c15) * 56 + g * 8);

        int kk0 = C * 32 + 4 * g;
        int a22 = kk0 / 22;
        int uc0 = kk0 - a22 * 22;
        int urx[2][4]; unsigned int cb[2][4];
        #pragma unroll
        for (int kt = 0; kt < 2; ++kt)
            #pragma unroll
            for (int r = 0; r < 4; ++r) {
                int x = uc0 + kt * 16 + r;
                int wrp = x >= 22;
                int uc = x - (wrp ? 22 : 0);
                urx[kt][r] = a22 + wrp;
                cb[kt][r] = (cm >> uc) & 1u;
            }

        #pragma unroll
        for (int qt = 0; qt < 4; ++qt) {
            f32x4 s0 = {}, s1 = {};
            s0 = __builtin_amdgcn_mfma_f32_16x16x32_bf16(ka[0][0], qf[qt][0], s0, 0, 0, 0);
            s0 = __builtin_amdgcn_mfma_f32_16x16x32_bf16(ka[0][1], qf[qt][1], s0, 0, 0, 0);
            s1 = __builtin_amdgcn_mfma_f32_16x16x32_bf16(ka[1][0], qf[qt][0], s1, 0, 0, 0);
            s1 = __builtin_amdgcn_mfma_f32_16x16x32_bf16(ka[1][1], qf[qt][1], s1, 0, 0, 0);
            float p[2][4];
            #pragma unroll
            for (int r = 0; r < 4; ++r) {
                float e0 = exp2f(s0[r]);
                float e1 = exp2f(s1[r]);
                p[0][r] = ((rm[qt] >> urx[0][r]) & cb[0][r]) ? e0 : 0.f;
                p[1][r] = ((rm[qt] >> urx[1][r]) & cb[1][r]) ? e1 : 0.f;
                spart[qt] += p[0][r] + p[1][r];
            }
            unsigned int pk[4];
            asm("v_cvt_pk_bf16_f32 %0, %1, %2" : "=v"(pk[0]) : "v"(p[0][0]), "v"(p[0][1]));
            asm("v_cvt_pk_bf16_f32 %0, %1, %2" : "=v"(pk[1]) : "v"(p[0][2]), "v"(p[0][3]));
            asm("v_cvt_pk_bf16_f32 %0, %1, %2" : "=v"(pk[2]) : "v"(p[1][0]), "v"(p[1][1]));
            asm("v_cvt_pk_bf16_f32 %0, %1, %2" : "=v"(pk[3]) : "v"(p[1][2]), "v"(p[1][3]));
            bf16x8 pa = *(bf16x8*)pk;
            #pragma unroll
            for (int dt = 0; dt < 4; ++dt)
                oacc[qt][dt] = __builtin_amdgcn_mfma_f32_16x16x32_bf16(pa, vb[dt], oacc[qt][dt], 0, 0, 0);
        }

        if (C < 6) {
            #pragma unroll
            for (int i = 0; i < 4; ++i) *(u16x8*)(Kl + sr * 72 + h5 * 32 + i * 8) = kst[i];
            #pragma unroll
            for (int i = 0; i < 4; ++i)
                #pragma unroll
                for (int e = 0; e < 8; ++e)
                    Vt[(h5 * 32 + i * 8 + e) * 56 + sig] = vst[i][e];
        }
    }

    #pragma unroll
    for (int qt = 0; qt < 4; ++qt) {
        float s = spart[qt];
        s += __shfl_xor(s, 16);
        s += __shfl_xor(s, 32);
        #pragma unroll
        for (int r = 0; r < 4; ++r) {
            float sb = __shfl(s, 4 * g + r);
            float inv = __builtin_amdgcn_rcpf(sb);
            size_t obase = (size_t)(pixbase + (pi0 + qt) * 64 + tj + 4 * g + r) * EMBED
                         + h * HDIM + c15;
            #pragma unroll
            for (int dt = 0; dt < 4; ++dt)
                attn_bf[obase + dt * 16] = f2bf(oacc[qt][dt][r] * inv);
        }
    }
}

// ---------------- launch ----------------
extern "C" void kernel_launch(void* const* d_in, const int* in_sizes, int n_in,
                              void* d_out, int out_size, void* d_ws, size_t ws_size,
                              hipStream_t stream)
{
    const float* x      = (const float*)d_in[0];
    const float* w_qkv  = (const float*)d_in[1];
    const float* b_qkv  = (const float*)d_in[2];
    const float* w_proj = (const float*)d_in[3];
    const float* b_proj = (const float*)d_in[4];
    float* out = (float*)d_out;

    // workspace (~206 MB)
    char* p = (char*)d_ws;
    unsigned short* qkv = (unsigned short*)p;     p += (size_t)NTOK * QKV_N * 2;       // 151 MB
    unsigned short* xbf = (unsigned short*)p;     // aliased: x_bf then attn_bf
    unsigned short* attn_bf = xbf;                p += (size_t)NTOK * EMBED * 2;       // 50 MB
    unsigned short* wq_bf = (unsigned short*)p;   p += (size_t)QKV_N * EMBED * 2;      // 3.5 MB
    unsigned short* wp_bf = (unsigned short*)p;

    const float scale = 0.125f * 1.44269504088896f;  // HDIM^-0.5 * log2(e)

    {
        int n4 = NTOK * EMBED / 4;
        cvt_bf16_kernel<<<(n4 + 255) / 256, 256, 0, stream>>>(x, xbf, n4);
        n4 = QKV_N * EMBED / 4;
        cvt_bf16_kernel<<<(n4 + 255) / 256, 256, 0, stream>>>(w_qkv, wq_bf, n4);
        n4 = EMBED * EMBED / 4;
        cvt_bf16_kernel<<<(n4 + 255) / 256, 256, 0, stream>>>(w_proj, wp_bf, n4);
    }

    {
        // GEMM1: M=32768, N=2304 -> 1152 blocks; per XCD: 16 bm-groups x 9 bn
        gemm256<1><<<(NTOK / 256) * (QKV_N / 256), 512, 0, stream>>>(
            xbf, wq_bf, b_qkv, qkv, NTOK, QKV_N, EMBED, EMBED, scale);
    }

    natten_kernel<<<BATCH * NHEADS * 16, 256, 0, stream>>>(qkv, attn_bf);

    {
        // GEMM2: M=32768, N=768 -> 384 blocks; per XCD: 16 bm-groups x 3 bn
        gemm256<0><<<(NTOK / 256) * (EMBED / 256), 512, 0, stream>>>(
            attn_bf, wp_bf, b_proj, out, NTOK, EMBED, EMBED, 0, 1.0f);
    }
}